// Round 9
// baseline (234.802 us; speedup 1.0000x reference)
//
#include <hip/hip_runtime.h>
#include <hip/hip_bf16.h>
#include <hip/hip_cooperative_groups.h>
#include <math.h>

namespace cg = cooperative_groups;

// B=1, H=16, L=2048, D=64. Chunked gated recurrence, chunk C=64, NC=32.
// Single cooperative kernel, 3 phases with 2 grid syncs:
//  P1 (per chunk): gradl + QK^T + decay + Intra(regs) + U^T -> Ut, Gc
//  P2 (blocks<256): 32-step chunk-state scan Ut->Wpt (L3-hot)
//  P3 (per chunk): Zq = exp(cl)*(q@Wprev) + Intra ; LN fwd ; +q -> Out
// Registers carried across syncs: split-q A-frags (reused in P3), Intra fi[4],
// cli (per-row Pg = expf(cli)), gamma/beta. Out is written exactly once (P3).
// All 64^3 matmuls: v_mfma_f32_16x16x32_bf16, FULL hi/lo split-bf16 (3-MFMA
// emulation ~2^-17 rel err) on every operand (LN amplifies relative error).
// LDS: 6 bf16 tiles [64][128B], XOR-swizzled (byte ^= (row&7)<<4) = 49.7KB.
// A row-major [M][K], B transposed [N][K]: every fragment one ds_read_b128.
// C/D: row = 4*(l>>4)+reg, col = l&15 (m89-verified).
// Fallback: if cooperative launch fails, R8's proven 3-kernel path runs.

#define H 16
#define L 2048
#define D 64
#define C 64
#define NC 32

typedef short s8v __attribute__((ext_vector_type(8)));
typedef short s4v __attribute__((ext_vector_type(4)));
typedef float f4v __attribute__((ext_vector_type(4)));

__device__ inline unsigned short f2bf(float x) {
  unsigned u = __float_as_uint(x);
  return (unsigned short)((u + 0x7fffu + ((u >> 16) & 1u)) >> 16);
}
__device__ inline float bf2f(unsigned short s) { return __uint_as_float(((unsigned)s) << 16); }

__device__ inline int swz(int row, int colByte) { return row * 128 + (colByte ^ ((row & 7) << 4)); }

__device__ inline s8v ld8(const short* base, int row, int colByte) {
  return *(const s8v*)((const char*)base + swz(row, colByte));
}
__device__ inline void st4(short* base, int row, int colByte, s4v v) {
  *(s4v*)((char*)base + swz(row, colByte)) = v;
}
__device__ inline void st2(short* base, int row, int colByte, unsigned v) {
  *(unsigned*)((char*)base + swz(row, colByte)) = v;
}
__device__ inline void st1(short* base, int row, int colByte, unsigned short v) {
  *(short*)((char*)base + swz(row, colByte)) = (short)v;
}

__device__ inline void red16(float& x) {
  x += __shfl_xor(x, 1, 64);
  x += __shfl_xor(x, 2, 64);
  x += __shfl_xor(x, 4, 64);
  x += __shfl_xor(x, 8, 64);
}

__device__ inline f4v MM(s8v a, s8v b, f4v c) {
  return __builtin_amdgcn_mfma_f32_16x16x32_bf16(a, b, c, 0, 0, 0);
}
__device__ inline f4v MM3(s8v ah, s8v al, s8v bh, s8v bl, f4v c) {
  c = MM(ah, bh, c);
  c = MM(ah, bl, c);
  c = MM(al, bh, c);
  return c;
}

// ================= fused cooperative kernel =================
__global__ __launch_bounds__(256, 2) void k_fused(
    const float4* __restrict__ Q4, const float4* __restrict__ K4,
    const float* __restrict__ Kg, const float* __restrict__ Vg,
    const float* __restrict__ gate, const float* __restrict__ eta,
    const float4* __restrict__ W04, const float* __restrict__ gamma,
    const float* __restrict__ beta, const float* __restrict__ W0f,
    const float* __restrict__ Qg,
    float* __restrict__ Ut, float* __restrict__ Gc, float* __restrict__ Wpt,
    float* __restrict__ Out)
{
  __shared__ __align__(16) short Khi[4096];  // k hi; P1 after bar2: S hi; P3: W^T hi
  __shared__ __align__(16) short Klo[4096];  // k lo; P1 after bar2: S lo; P3: W^T lo
  __shared__ __align__(16) short KtH[4096];  // (wj*k)^T hi (B M4)
  __shared__ __align__(16) short KtL[4096];  // (wj*k)^T lo
  __shared__ __align__(16) short W0h[4096];  // W0^T hi (B M2); after bar2: gt^T hi
  __shared__ __align__(16) short W0l[4096];  // W0^T lo;        after bar2: gt^T lo
  __shared__ float cl[64], wj[64];

  int tid = threadIdx.x;
  int bid = blockIdx.x;
  int h = bid >> 5, c = bid & 31;
  int rowb = h * L + c * C;
  int R = tid >> 6, l = tid & 63, g = l >> 4, c16 = l & 15;
  int arow = 16 * R + c16;
  int kb0 = 16 * g, kb1 = 64 + 16 * g;

  // ---- early global loads
  const float4* qp = Q4 + (size_t)(rowb + arow) * 16;
  float4 qA0 = qp[2 * g], qA1 = qp[2 * g + 1], qA2 = qp[8 + 2 * g], qA3 = qp[8 + 2 * g + 1];
  float kk[4][4], vv[4][4], er[4];
  #pragma unroll
  for (int r = 0; r < 4; ++r) {
    int jr = 16 * R + 4 * g + r;
    const float* kp = Kg + (size_t)(rowb + jr) * 64 + c16;
    const float* vp = Vg + (size_t)(rowb + jr) * 64 + c16;
    #pragma unroll
    for (int ct = 0; ct < 4; ++ct) {
      kk[r][ct] = kp[16 * ct];
      vv[r][ct] = vp[16 * ct];
    }
    er[r] = eta[rowb + jr];
  }

  // ---- gate log-cumsum (redundant per wave; each wave reads own writes)
  {
    float x = logf(fmaxf(gate[rowb + l], 1e-37f));
    #pragma unroll
    for (int off = 1; off < 64; off <<= 1) {
      float n = __shfl_up(x, off, 64);
      if (l >= off) x += n;
    }
    cl[l] = x;
    float c63 = __shfl(x, 63, 64);
    wj[l] = expf(c63 - x);
    if (tid == 63) Gc[bid] = expf(x);   // chunk gate product for the scan
  }

  // ---- stage k rows hi/lo, (wj*k)^T, W0^T (b32-packed row pairs)
  #pragma unroll
  for (int it = 0; it < 2; ++it) {
    int idx = tid + it * 256;
    int rp = idx >> 4, g4 = idx & 15;
    int j0 = 2 * rp, j1 = j0 + 1;
    float4 k0 = K4[(size_t)(rowb + j0) * 16 + g4];
    float4 k1 = K4[(size_t)(rowb + j1) * 16 + g4];
    float4 w0 = W04[(size_t)h * 1024 + j0 * 16 + g4];
    float4 w1 = W04[(size_t)h * 1024 + j1 * 16 + g4];
    float w0j = wj[j0], w1j = wj[j1];
    float ke0[4] = {k0.x, k0.y, k0.z, k0.w};
    float ke1[4] = {k1.x, k1.y, k1.z, k1.w};
    float we0[4] = {w0.x, w0.y, w0.z, w0.w};
    float we1[4] = {w1.x, w1.y, w1.z, w1.w};
    s4v kh0, kl0, kh1, kl1;
    #pragma unroll
    for (int e = 0; e < 4; ++e) {
      unsigned short hb0 = f2bf(ke0[e]);
      kh0[e] = (short)hb0; kl0[e] = (short)f2bf(ke0[e] - bf2f(hb0));
      unsigned short hb1 = f2bf(ke1[e]);
      kh1[e] = (short)hb1; kl1[e] = (short)f2bf(ke1[e] - bf2f(hb1));
      int dr = 4 * g4 + e;
      float wk0 = ke0[e] * w0j, wk1 = ke1[e] * w1j;
      unsigned short th0 = f2bf(wk0), th1 = f2bf(wk1);
      st2(KtH, dr, 2 * j0, (unsigned)th0 | ((unsigned)th1 << 16));
      st2(KtL, dr, 2 * j0,
          (unsigned)f2bf(wk0 - bf2f(th0)) | ((unsigned)f2bf(wk1 - bf2f(th1)) << 16));
      unsigned short wh0 = f2bf(we0[e]), wh1 = f2bf(we1[e]);
      st2(W0h, dr, 2 * j0, (unsigned)wh0 | ((unsigned)wh1 << 16));
      st2(W0l, dr, 2 * j0,
          (unsigned)f2bf(we0[e] - bf2f(wh0)) | ((unsigned)f2bf(we1[e] - bf2f(wh1)) << 16));
    }
    st4(Khi, j0, 8 * g4, kh0); st4(Klo, j0, 8 * g4, kl0);
    st4(Khi, j1, 8 * g4, kh1); st4(Klo, j1, 8 * g4, kl1);
  }

  // ---- split q A-fragments in registers (kept through P3)
  s8v aQh0, aQl0, aQh1, aQl1;
  {
    float q0[8] = {qA0.x, qA0.y, qA0.z, qA0.w, qA1.x, qA1.y, qA1.z, qA1.w};
    float q1[8] = {qA2.x, qA2.y, qA2.z, qA2.w, qA3.x, qA3.y, qA3.z, qA3.w};
    #pragma unroll
    for (int e = 0; e < 8; ++e) {
      unsigned short hb = f2bf(q0[e]);
      aQh0[e] = (short)hb; aQl0[e] = (short)f2bf(q0[e] - bf2f(hb));
      unsigned short hb1 = f2bf(q1[e]);
      aQh1[e] = (short)hb1; aQl1[e] = (short)f2bf(q1[e] - bf2f(hb1));
    }
  }
  __syncthreads();   // bar1: tiles staged

  // ---- M1: S = QK^T (split x split)
  f4v accS[4];
  #pragma unroll
  for (int ct = 0; ct < 4; ++ct) {
    int br = 16 * ct + c16;
    f4v a = {0.f, 0.f, 0.f, 0.f};
    a = MM3(aQh0, aQl0, ld8(Khi, br, kb0), ld8(Klo, br, kb0), a);
    a = MM3(aQh1, aQl1, ld8(Khi, br, kb1), ld8(Klo, br, kb1), a);
    accS[ct] = a;
  }

  // ---- M2: Z1 = K @ W0 (split x split)
  s8v aKh0 = ld8(Khi, arow, kb0), aKh1 = ld8(Khi, arow, kb1);
  s8v aKl0 = ld8(Klo, arow, kb0), aKl1 = ld8(Klo, arow, kb1);
  f4v accZ[4];
  #pragma unroll
  for (int ct = 0; ct < 4; ++ct) {
    int br = 16 * ct + c16;
    f4v a = {0.f, 0.f, 0.f, 0.f};
    a = MM3(aKh0, aKl0, ld8(W0h, br, kb0), ld8(W0l, br, kb0), a);
    a = MM3(aKh1, aKl1, ld8(W0h, br, kb1), ld8(W0l, br, kb1), a);
    accZ[ct] = a;
  }

  // ---- LN-L2 backward; k,v,eta in regs
  float ga[4], be[4];
  #pragma unroll
  for (int ct = 0; ct < 4; ++ct) {
    ga[ct] = gamma[h * 64 + 16 * ct + c16];
    be[ct] = beta[h * 64 + 16 * ct + c16];
  }
  float gtreg[4][4];
  #pragma unroll
  for (int r = 0; r < 4; ++r) {
    float s1 = accZ[0][r] + accZ[1][r] + accZ[2][r] + accZ[3][r];
    red16(s1);
    float mu = s1 * (1.f / 64.f);
    float dv[4], s2 = 0.f;
    #pragma unroll
    for (int ct = 0; ct < 4; ++ct) { dv[ct] = accZ[ct][r] - mu; s2 += dv[ct] * dv[ct]; }
    red16(s2);
    float rstd = rsqrtf(s2 * (1.f / 64.f) + 1e-6f);
    float xh[4], gxh[4], t1 = 0.f, t2 = 0.f;
    #pragma unroll
    for (int ct = 0; ct < 4; ++ct) {
      xh[ct] = dv[ct] * rstd;
      float go = 2.f * (fmaf(ga[ct], xh[ct], be[ct]) + kk[r][ct] - vv[r][ct]);
      gxh[ct] = go * ga[ct];
      t1 += gxh[ct];
      t2 += gxh[ct] * xh[ct];
    }
    red16(t1);
    red16(t2);
    float m1 = t1 * (1.f / 64.f), m2 = t2 * (1.f / 64.f);
    #pragma unroll
    for (int ct = 0; ct < 4; ++ct)
      gtreg[r][ct] = -er[r] * (gxh[ct] - m1 - xh[ct] * m2) * rstd;
  }
  __syncthreads();   // bar2: K/W0 tiles dead

  // ---- gt^T into W0 tiles; decayed+masked S into K tiles
  #pragma unroll
  for (int ct = 0; ct < 4; ++ct) {
    s4v gh, gl;
    #pragma unroll
    for (int r = 0; r < 4; ++r) {
      unsigned short hb = f2bf(gtreg[r][ct]);
      gh[r] = (short)hb;
      gl[r] = (short)f2bf(gtreg[r][ct] - bf2f(hb));
    }
    st4(W0h, 16 * ct + c16, 2 * (16 * R + 4 * g), gh);
    st4(W0l, 16 * ct + c16, 2 * (16 * R + 4 * g), gl);
  }
  float cli[4];
  #pragma unroll
  for (int r = 0; r < 4; ++r) cli[r] = cl[16 * R + 4 * g + r];
  #pragma unroll
  for (int ct = 0; ct < 4; ++ct) {
    int j = 16 * ct + c16;
    float clj = cl[j];
    #pragma unroll
    for (int r = 0; r < 4; ++r) {
      int i = 16 * R + 4 * g + r;
      float s = (j <= i) ? accS[ct][r] * expf(cli[r] - clj) : 0.f;
      unsigned short hb = f2bf(s);
      st1(Khi, i, 2 * j, hb);
      st1(Klo, i, 2 * j, f2bf(s - bf2f(hb)));
    }
  }
  __syncthreads();   // bar3

  // ---- M3: Intra -> REGISTERS (fi), no global write
  f4v fi[4];
  s8v aSh0 = ld8(Khi, arow, kb0), aSh1 = ld8(Khi, arow, kb1);
  s8v aSl0 = ld8(Klo, arow, kb0), aSl1 = ld8(Klo, arow, kb1);
  #pragma unroll
  for (int ct = 0; ct < 4; ++ct) {
    int br = 16 * ct + c16;
    f4v a = {0.f, 0.f, 0.f, 0.f};
    a = MM3(aSh0, aSl0, ld8(W0h, br, kb0), ld8(W0l, br, kb0), a);
    a = MM3(aSh1, aSl1, ld8(W0h, br, kb1), ld8(W0l, br, kb1), a);
    fi[ct] = a;
  }

  // ---- M4: U^T -> Ut
  float* ub = Ut + (size_t)bid * 4096;
  s8v aGh0 = ld8(W0h, arow, kb0), aGh1 = ld8(W0h, arow, kb1);
  s8v aGl0 = ld8(W0l, arow, kb0), aGl1 = ld8(W0l, arow, kb1);
  #pragma unroll
  for (int ct = 0; ct < 4; ++ct) {
    int br = 16 * ct + c16;
    f4v a = {0.f, 0.f, 0.f, 0.f};
    a = MM3(aGh0, aGl0, ld8(KtH, br, kb0), ld8(KtL, br, kb0), a);
    a = MM3(aGh1, aGl1, ld8(KtH, br, kb1), ld8(KtL, br, kb1), a);
    #pragma unroll
    for (int r = 0; r < 4; ++r)
      ub[(16 * R + 4 * g + r) * 64 + 16 * ct + c16] = a[r];
  }

  __threadfence();
  cg::this_grid().sync();   // ---- sync 1: Ut, Gc visible

  // ---- P2: chunk-state scan (blocks 0..255)
  if (bid < 256) {
    int t = bid * 256 + tid;
    int hh = t >> 12, idx = t & 4095;
    int erow = idx >> 6, d = idx & 63;
    float w = W0f[hh * 4096 + d * 64 + erow];   // W0^T element
    #pragma unroll
    for (int c2 = 0; c2 < NC; ++c2) {
      int off = (hh * NC + c2) * 4096 + idx;
      Wpt[off] = w;
      w = fmaf(Gc[hh * NC + c2], w, Ut[off]);
    }
  }

  __threadfence();
  cg::this_grid().sync();   // ---- sync 2: Wpt visible

  // ---- P3: readout. Stage Wprev^T split into K tiles; q frags reused.
  {
    const float4* wp4 = (const float4*)Wpt + (size_t)bid * 1024;
    for (int idx = tid; idx < 1024; idx += 256) {
      int row = idx >> 4, g4 = idx & 15;
      float4 wv = wp4[idx];
      float we[4] = {wv.x, wv.y, wv.z, wv.w};
      s4v wh, wl;
      #pragma unroll
      for (int e = 0; e < 4; ++e) {
        unsigned short hb = f2bf(we[e]);
        wh[e] = (short)hb;
        wl[e] = (short)f2bf(we[e] - bf2f(hb));
      }
      st4(Khi, row, 8 * g4, wh);
      st4(Klo, row, 8 * g4, wl);
    }
    float qres[4][4], pr4[4];
    #pragma unroll
    for (int r = 0; r < 4; ++r) {
      int row = rowb + 16 * R + 4 * g + r;
      pr4[r] = expf(cli[r]);
      #pragma unroll
      for (int ct = 0; ct < 4; ++ct)
        qres[r][ct] = Qg[(size_t)row * 64 + 16 * ct + c16];
    }
    __syncthreads();

    f4v acc[4];
    #pragma unroll
    for (int ct = 0; ct < 4; ++ct) {
      int br = 16 * ct + c16;
      f4v a = {0.f, 0.f, 0.f, 0.f};
      a = MM3(aQh0, aQl0, ld8(Khi, br, kb0), ld8(Klo, br, kb0), a);
      a = MM3(aQh1, aQl1, ld8(Khi, br, kb1), ld8(Klo, br, kb1), a);
      acc[ct] = a;
    }
    #pragma unroll
    for (int r = 0; r < 4; ++r) {
      int row = rowb + 16 * R + 4 * g + r;
      float zq[4];
      #pragma unroll
      for (int ct = 0; ct < 4; ++ct)
        zq[ct] = fmaf(pr4[r], acc[ct][r], fi[ct][r]);
      float s1 = zq[0] + zq[1] + zq[2] + zq[3];
      red16(s1);
      float mu = s1 * (1.f / 64.f);
      float dv[4], s2 = 0.f;
      #pragma unroll
      for (int ct = 0; ct < 4; ++ct) { dv[ct] = zq[ct] - mu; s2 += dv[ct] * dv[ct]; }
      red16(s2);
      float rstd = rsqrtf(s2 * (1.f / 64.f) + 1e-6f);
      #pragma unroll
      for (int ct = 0; ct < 4; ++ct) {
        float o = fmaf(ga[ct], dv[ct] * rstd, be[ct]) + qres[r][ct];
        Out[(size_t)row * 64 + 16 * ct + c16] = o;
      }
    }
  }
}

// ================= fallback path (R8's proven 3-kernel pipeline) =================
__global__ __launch_bounds__(256, 2) void k_chunk(
    const float4* __restrict__ Q4, const float4* __restrict__ K4,
    const float* __restrict__ Kg, const float* __restrict__ Vg,
    const float* __restrict__ gate, const float* __restrict__ eta,
    const float4* __restrict__ W04, const float* __restrict__ gamma,
    const float* __restrict__ beta,
    float* __restrict__ Ut, float* __restrict__ Pg, float* __restrict__ Out)
{
  __shared__ __align__(16) short Khi[4096];
  __shared__ __align__(16) short Klo[4096];
  __shared__ __align__(16) short KtH[4096];
  __shared__ __align__(16) short KtL[4096];
  __shared__ __align__(16) short W0h[4096];
  __shared__ __align__(16) short W0l[4096];
  __shared__ float cl[64], wj[64];

  int tid = threadIdx.x;
  int h = blockIdx.x >> 5, c = blockIdx.x & 31;
  int rowb = h * L + c * C;
  int R = tid >> 6, l = tid & 63, g = l >> 4, c16 = l & 15;
  int arow = 16 * R + c16;
  int kb0 = 16 * g, kb1 = 64 + 16 * g;

  const float4* qp = Q4 + (size_t)(rowb + arow) * 16;
  float4 qA0 = qp[2 * g], qA1 = qp[2 * g + 1], qA2 = qp[8 + 2 * g], qA3 = qp[8 + 2 * g + 1];
  float kk[4][4], vv[4][4], er[4];
  #pragma unroll
  for (int r = 0; r < 4; ++r) {
    int jr = 16 * R + 4 * g + r;
    const float* kp = Kg + (size_t)(rowb + jr) * 64 + c16;
    const float* vp = Vg + (size_t)(rowb + jr) * 64 + c16;
    #pragma unroll
    for (int ct = 0; ct < 4; ++ct) { kk[r][ct] = kp[16 * ct]; vv[r][ct] = vp[16 * ct]; }
    er[r] = eta[rowb + jr];
  }
  {
    float x = logf(fmaxf(gate[rowb + l], 1e-37f));
    #pragma unroll
    for (int off = 1; off < 64; off <<= 1) {
      float n = __shfl_up(x, off, 64);
      if (l >= off) x += n;
    }
    cl[l] = x;
    float c63 = __shfl(x, 63, 64);
    wj[l] = expf(c63 - x);
    if (R == 0) Pg[rowb + l] = expf(x);
  }
  #pragma unroll
  for (int it = 0; it < 2; ++it) {
    int idx = tid + it * 256;
    int rp = idx >> 4, g4 = idx & 15;
    int j0 = 2 * rp, j1 = j0 + 1;
    float4 k0 = K4[(size_t)(rowb + j0) * 16 + g4];
    float4 k1 = K4[(size_t)(rowb + j1) * 16 + g4];
    float4 w0 = W04[(size_t)h * 1024 + j0 * 16 + g4];
    float4 w1 = W04[(size_t)h * 1024 + j1 * 16 + g4];
    float w0j = wj[j0], w1j = wj[j1];
    float ke0[4] = {k0.x, k0.y, k0.z, k0.w};
    float ke1[4] = {k1.x, k1.y, k1.z, k1.w};
    float we0[4] = {w0.x, w0.y, w0.z, w0.w};
    float we1[4] = {w1.x, w1.y, w1.z, w1.w};
    s4v kh0, kl0, kh1, kl1;
    #pragma unroll
    for (int e = 0; e < 4; ++e) {
      unsigned short hb0 = f2bf(ke0[e]);
      kh0[e] = (short)hb0; kl0[e] = (short)f2bf(ke0[e] - bf2f(hb0));
      unsigned short hb1 = f2bf(ke1[e]);
      kh1[e] = (short)hb1; kl1[e] = (short)f2bf(ke1[e] - bf2f(hb1));
      int dr = 4 * g4 + e;
      float wk0 = ke0[e] * w0j, wk1 = ke1[e] * w1j;
      unsigned short th0 = f2bf(wk0), th1 = f2bf(wk1);
      st2(KtH, dr, 2 * j0, (unsigned)th0 | ((unsigned)th1 << 16));
      st2(KtL, dr, 2 * j0,
          (unsigned)f2bf(wk0 - bf2f(th0)) | ((unsigned)f2bf(wk1 - bf2f(th1)) << 16));
      unsigned short wh0 = f2bf(we0[e]), wh1 = f2bf(we1[e]);
      st2(W0h, dr, 2 * j0, (unsigned)wh0 | ((unsigned)wh1 << 16));
      st2(W0l, dr, 2 * j0,
          (unsigned)f2bf(we0[e] - bf2f(wh0)) | ((unsigned)f2bf(we1[e] - bf2f(wh1)) << 16));
    }
    st4(Khi, j0, 8 * g4, kh0); st4(Klo, j0, 8 * g4, kl0);
    st4(Khi, j1, 8 * g4, kh1); st4(Klo, j1, 8 * g4, kl1);
  }
  s8v aQh0, aQl0, aQh1, aQl1;
  {
    float q0[8] = {qA0.x, qA0.y, qA0.z, qA0.w, qA1.x, qA1.y, qA1.z, qA1.w};
    float q1[8] = {qA2.x, qA2.y, qA2.z, qA2.w, qA3.x, qA3.y, qA3.z, qA3.w};
    #pragma unroll
    for (int e = 0; e < 8; ++e) {
      unsigned short hb = f2bf(q0[e]);
      aQh0[e] = (short)hb; aQl0[e] = (short)f2bf(q0[e] - bf2f(hb));
      unsigned short hb1 = f2bf(q1[e]);
      aQh1[e] = (short)hb1; aQl1[e] = (short)f2bf(q1[e] - bf2f(hb1));
    }
  }
  __syncthreads();
  f4v accS[4];
  #pragma unroll
  for (int ct = 0; ct < 4; ++ct) {
    int br = 16 * ct + c16;
    f4v a = {0.f, 0.f, 0.f, 0.f};
    a = MM3(aQh0, aQl0, ld8(Khi, br, kb0), ld8(Klo, br, kb0), a);
    a = MM3(aQh1, aQl1, ld8(Khi, br, kb1), ld8(Klo, br, kb1), a);
    accS[ct] = a;
  }
  s8v aKh0 = ld8(Khi, arow, kb0), aKh1 = ld8(Khi, arow, kb1);
  s8v aKl0 = ld8(Klo, arow, kb0), aKl1 = ld8(Klo, arow, kb1);
  f4v accZ[4];
  #pragma unroll
  for (int ct = 0; ct < 4; ++ct) {
    int br = 16 * ct + c16;
    f4v a = {0.f, 0.f, 0.f, 0.f};
    a = MM3(aKh0, aKl0, ld8(W0h, br, kb0), ld8(W0l, br, kb0), a);
    a = MM3(aKh1, aKl1, ld8(W0h, br, kb1), ld8(W0l, br, kb1), a);
    accZ[ct] = a;
  }
  float ga[4], be[4];
  #pragma unroll
  for (int ct = 0; ct < 4; ++ct) {
    ga[ct] = gamma[h * 64 + 16 * ct + c16];
    be[ct] = beta[h * 64 + 16 * ct + c16];
  }
  float gtreg[4][4];
  #pragma unroll
  for (int r = 0; r < 4; ++r) {
    float s1 = accZ[0][r] + accZ[1][r] + accZ[2][r] + accZ[3][r];
    red16(s1);
    float mu = s1 * (1.f / 64.f);
    float dv[4], s2 = 0.f;
    #pragma unroll
    for (int ct = 0; ct < 4; ++ct) { dv[ct] = accZ[ct][r] - mu; s2 += dv[ct] * dv[ct]; }
    red16(s2);
    float rstd = rsqrtf(s2 * (1.f / 64.f) + 1e-6f);
    float xh[4], gxh[4], t1 = 0.f, t2 = 0.f;
    #pragma unroll
    for (int ct = 0; ct < 4; ++ct) {
      xh[ct] = dv[ct] * rstd;
      float go = 2.f * (fmaf(ga[ct], xh[ct], be[ct]) + kk[r][ct] - vv[r][ct]);
      gxh[ct] = go * ga[ct];
      t1 += gxh[ct];
      t2 += gxh[ct] * xh[ct];
    }
    red16(t1);
    red16(t2);
    float m1 = t1 * (1.f / 64.f), m2 = t2 * (1.f / 64.f);
    #pragma unroll
    for (int ct = 0; ct < 4; ++ct)
      gtreg[r][ct] = -er[r] * (gxh[ct] - m1 - xh[ct] * m2) * rstd;
  }
  __syncthreads();
  #pragma unroll
  for (int ct = 0; ct < 4; ++ct) {
    s4v gh, gl;
    #pragma unroll
    for (int r = 0; r < 4; ++r) {
      unsigned short hb = f2bf(gtreg[r][ct]);
      gh[r] = (short)hb;
      gl[r] = (short)f2bf(gtreg[r][ct] - bf2f(hb));
    }
    st4(W0h, 16 * ct + c16, 2 * (16 * R + 4 * g), gh);
    st4(W0l, 16 * ct + c16, 2 * (16 * R + 4 * g), gl);
  }
  float cli[4];
  #pragma unroll
  for (int r = 0; r < 4; ++r) cli[r] = cl[16 * R + 4 * g + r];
  #pragma unroll
  for (int ct = 0; ct < 4; ++ct) {
    int j = 16 * ct + c16;
    float clj = cl[j];
    #pragma unroll
    for (int r = 0; r < 4; ++r) {
      int i = 16 * R + 4 * g + r;
      float s = (j <= i) ? accS[ct][r] * expf(cli[r] - clj) : 0.f;
      unsigned short hb = f2bf(s);
      st1(Khi, i, 2 * j, hb);
      st1(Klo, i, 2 * j, f2bf(s - bf2f(hb)));
    }
  }
  __syncthreads();
  s8v aSh0 = ld8(Khi, arow, kb0), aSh1 = ld8(Khi, arow, kb1);
  s8v aSl0 = ld8(Klo, arow, kb0), aSl1 = ld8(Klo, arow, kb1);
  #pragma unroll
  for (int ct = 0; ct < 4; ++ct) {
    int br = 16 * ct + c16;
    f4v a = {0.f, 0.f, 0.f, 0.f};
    a = MM3(aSh0, aSl0, ld8(W0h, br, kb0), ld8(W0l, br, kb0), a);
    a = MM3(aSh1, aSl1, ld8(W0h, br, kb1), ld8(W0l, br, kb1), a);
    #pragma unroll
    for (int r = 0; r < 4; ++r)
      Out[(size_t)(rowb + 16 * R + 4 * g + r) * 64 + 16 * ct + c16] = a[r];
  }
  float* ub = Ut + (size_t)(h * NC + c) * 4096;
  s8v aGh0 = ld8(W0h, arow, kb0), aGh1 = ld8(W0h, arow, kb1);
  s8v aGl0 = ld8(W0l, arow, kb0), aGl1 = ld8(W0l, arow, kb1);
  #pragma unroll
  for (int ct = 0; ct < 4; ++ct) {
    int br = 16 * ct + c16;
    f4v a = {0.f, 0.f, 0.f, 0.f};
    a = MM3(aGh0, aGl0, ld8(KtH, br, kb0), ld8(KtL, br, kb0), a);
    a = MM3(aGh1, aGl1, ld8(KtH, br, kb1), ld8(KtL, br, kb1), a);
    #pragma unroll
    for (int r = 0; r < 4; ++r)
      ub[(16 * R + 4 * g + r) * 64 + 16 * ct + c16] = a[r];
  }
}

__global__ __launch_bounds__(256) void k_scan(
    const float* __restrict__ W0, const float* __restrict__ Ut,
    const float* __restrict__ Pg, float* __restrict__ Wpt)
{
  int t = blockIdx.x * 256 + threadIdx.x;
  int h = t >> 12;
  int idx = t & 4095;
  int erow = idx >> 6, d = idx & 63;
  float w = W0[h * 4096 + d * 64 + erow];
  #pragma unroll
  for (int c2 = 0; c2 < NC; ++c2) {
    int off = (h * NC + c2) * 4096 + idx;
    Wpt[off] = w;
    w = fmaf(Pg[h * L + c2 * 64 + 63], w, Ut[off]);
  }
}

__global__ __launch_bounds__(256, 2) void k_out(
    const float4* __restrict__ Q4, const float* __restrict__ Qg,
    const float4* __restrict__ Wpt4, const float* __restrict__ Pg,
    const float* __restrict__ gamma, const float* __restrict__ beta,
    float* __restrict__ Out)
{
  __shared__ __align__(16) short Whi[4096];
  __shared__ __align__(16) short Wlo[4096];
  int tid = threadIdx.x;
  int h = blockIdx.x >> 5, c = blockIdx.x & 31;
  int rowb = h * L + c * C;
  int R = tid >> 6, l = tid & 63, g = l >> 4, c16 = l & 15;
  int arow = 16 * R + c16;
  int kb0 = 16 * g, kb1 = 64 + 16 * g;
  const float4* qp = Q4 + (size_t)(rowb + arow) * 16;
  float4 qA0 = qp[2 * g], qA1 = qp[2 * g + 1], qA2 = qp[8 + 2 * g], qA3 = qp[8 + 2 * g + 1];
  float io[4][4], qres[4][4], pr[4];
  #pragma unroll
  for (int r = 0; r < 4; ++r) {
    int row = rowb + 16 * R + 4 * g + r;
    pr[r] = Pg[row];
    #pragma unroll
    for (int ct = 0; ct < 4; ++ct) {
      io[r][ct] = Out[(size_t)row * 64 + 16 * ct + c16];
      qres[r][ct] = Qg[(size_t)row * 64 + 16 * ct + c16];
    }
  }
  for (int idx = tid; idx < 1024; idx += 256) {
    int row = idx >> 4, g4 = idx & 15;
    float4 wv = Wpt4[(size_t)(h * NC + c) * 1024 + idx];
    float we[4] = {wv.x, wv.y, wv.z, wv.w};
    s4v wh, wl;
    #pragma unroll
    for (int e = 0; e < 4; ++e) {
      unsigned short hb = f2bf(we[e]);
      wh[e] = (short)hb;
      wl[e] = (short)f2bf(we[e] - bf2f(hb));
    }
    st4(Whi, row, 8 * g4, wh);
    st4(Wlo, row, 8 * g4, wl);
  }
  s8v ah0, al0, ah1, al1;
  {
    float q0[8] = {qA0.x, qA0.y, qA0.z, qA0.w, qA1.x, qA1.y, qA1.z, qA1.w};
    float q1[8] = {qA2.x, qA2.y, qA2.z, qA2.w, qA3.x, qA3.y, qA3.z, qA3.w};
    #pragma unroll
    for (int e = 0; e < 8; ++e) {
      unsigned short hb = f2bf(q0[e]);
      ah0[e] = (short)hb; al0[e] = (short)f2bf(q0[e] - bf2f(hb));
      unsigned short hb1 = f2bf(q1[e]);
      ah1[e] = (short)hb1; al1[e] = (short)f2bf(q1[e] - bf2f(hb1));
    }
  }
  __syncthreads();
  f4v acc[4];
  #pragma unroll
  for (int ct = 0; ct < 4; ++ct) {
    int br = 16 * ct + c16;
    f4v a = {0.f, 0.f, 0.f, 0.f};
    a = MM3(ah0, al0, ld8(Whi, br, kb0), ld8(Wlo, br, kb0), a);
    a = MM3(ah1, al1, ld8(Whi, br, kb1), ld8(Wlo, br, kb1), a);
    acc[ct] = a;
  }
  float ga[4], be[4];
  #pragma unroll
  for (int ct = 0; ct < 4; ++ct) {
    ga[ct] = gamma[h * 64 + 16 * ct + c16];
    be[ct] = beta[h * 64 + 16 * ct + c16];
  }
  #pragma unroll
  for (int r = 0; r < 4; ++r) {
    int row = rowb + 16 * R + 4 * g + r;
    float zq[4];
    #pragma unroll
    for (int ct = 0; ct < 4; ++ct)
      zq[ct] = fmaf(pr[r], acc[ct][r], io[r][ct]);
    float s1 = zq[0] + zq[1] + zq[2] + zq[3];
    red16(s1);
    float mu = s1 * (1.f / 64.f);
    float dv[4], s2 = 0.f;
    #pragma unroll
    for (int ct = 0; ct < 4; ++ct) { dv[ct] = zq[ct] - mu; s2 += dv[ct] * dv[ct]; }
    red16(s2);
    float rstd = rsqrtf(s2 * (1.f / 64.f) + 1e-6f);
    #pragma unroll
    for (int ct = 0; ct < 4; ++ct) {
      float o = fmaf(ga[ct], dv[ct] * rstd, be[ct]) + qres[r][ct];
      Out[(size_t)row * 64 + 16 * ct + c16] = o;
    }
  }
}

extern "C" void kernel_launch(void* const* d_in, const int* in_sizes, int n_in,
                              void* d_out, int out_size, void* d_ws, size_t ws_size,
                              hipStream_t stream) {
  const float* q     = (const float*)d_in[0];
  const float* k     = (const float*)d_in[1];
  const float* v     = (const float*)d_in[2];
  const float* gate  = (const float*)d_in[3];
  const float* eta   = (const float*)d_in[4];
  const float* W0    = (const float*)d_in[5];
  const float* gamma = (const float*)d_in[6];
  const float* beta  = (const float*)d_in[7];
  float* out = (float*)d_out;
  float* ws  = (float*)d_ws;

  float* Pg  = ws;                        // fallback: 32768 floats; fused: Gc 512
  float* Ut  = ws + 32768;                // 2097152 floats
  float* Wpt = ws + 32768 + 2097152;      // 2097152 floats

  const float4* q4  = (const float4*)q;
  const float4* k4  = (const float4*)k;
  const float4* w04 = (const float4*)W0;
  const float*  kg  = k;
  const float*  vg  = v;
  const float*  qg  = q;
  const float*  w0f = W0;
  float* Gc = Pg;

  void* args[] = {(void*)&q4, (void*)&k4, (void*)&kg, (void*)&vg,
                  (void*)&gate, (void*)&eta, (void*)&w04, (void*)&gamma,
                  (void*)&beta, (void*)&w0f, (void*)&qg,
                  (void*)&Ut, (void*)&Gc, (void*)&Wpt, (void*)&out};
  hipError_t err = hipLaunchCooperativeKernel(
      (const void*)k_fused, dim3(H * NC), dim3(256), args, 0, stream);

  if (err != hipSuccess) {
    // fallback: proven 3-kernel pipeline
    k_chunk<<<H * NC, 256, 0, stream>>>(
        q4, k4, kg, vg, gate, eta, w04, gamma, beta, Ut, Pg, out);
    k_scan<<<256, 256, 0, stream>>>(W0, Ut, Pg, Wpt);
    k_out<<<H * NC, 256, 0, stream>>>(
        q4, qg, (const float4*)Wpt, Pg, gamma, beta, out);
  }
}

// Round 10
// 78.197 us; speedup vs baseline: 3.0027x; 3.0027x over previous
//
#include <hip/hip_runtime.h>
#include <hip/hip_bf16.h>
#include <math.h>

// B=1, H=16, L=2048, D=64. Chunked gated recurrence, chunk C=64, NC=32.
// 2 dispatches:
//  k_chunk (512 blocks): gradl + QK^T + decay + Intra(->Out) + U^T(->Ut);
//    the LAST block of each head (atomic counter, no spinning) runs the
//    32-step chunk-state scan for that head (Ut L2-hot) -> Wpt.
//  k_out (512 blocks): Zq = Pg*(q@Wprev) + Intra ; LN fwd ; +q.
// Load-order discipline: gate first, then staging loads (first vmcnt waits
// drain only them), then q/k/v/eta prefetches (consumed later).
// All 64^3 matmuls: v_mfma_f32_16x16x32_bf16, FULL hi/lo split-bf16 (3-MFMA
// emulation ~2^-17 rel err) on every operand (LN amplifies relative error).
// LDS: 8 bf16 tiles [64][128B], XOR-swizzled (byte ^= (row&7)<<4) = 66KB,
// 2 blocks/CU. A row-major [M][K], B transposed [N][K]: one ds_read_b128 per
// fragment. C/D: row = 4*(l>>4)+reg, col = l&15 (m89-verified).

#define H 16
#define L 2048
#define D 64
#define NC 32

typedef short s8v __attribute__((ext_vector_type(8)));
typedef short s4v __attribute__((ext_vector_type(4)));
typedef float f4v __attribute__((ext_vector_type(4)));

__device__ inline unsigned short f2bf(float x) {
  unsigned u = __float_as_uint(x);
  return (unsigned short)((u + 0x7fffu + ((u >> 16) & 1u)) >> 16);
}
__device__ inline float bf2f(unsigned short s) { return __uint_as_float(((unsigned)s) << 16); }

__device__ inline int swz(int row, int colByte) { return row * 128 + (colByte ^ ((row & 7) << 4)); }

__device__ inline s8v ld8(const short* base, int row, int colByte) {
  return *(const s8v*)((const char*)base + swz(row, colByte));
}
__device__ inline void st4(short* base, int row, int colByte, s4v v) {
  *(s4v*)((char*)base + swz(row, colByte)) = v;
}
__device__ inline void st2(short* base, int row, int colByte, unsigned v) {
  *(unsigned*)((char*)base + swz(row, colByte)) = v;
}
__device__ inline void st1(short* base, int row, int colByte, unsigned short v) {
  *(short*)((char*)base + swz(row, colByte)) = (short)v;
}

__device__ inline void red16(float& x) {
  x += __shfl_xor(x, 1, 64);
  x += __shfl_xor(x, 2, 64);
  x += __shfl_xor(x, 4, 64);
  x += __shfl_xor(x, 8, 64);
}

__device__ inline f4v MM(s8v a, s8v b, f4v c) {
  return __builtin_amdgcn_mfma_f32_16x16x32_bf16(a, b, c, 0, 0, 0);
}
// 3-MFMA split product: (Ah+Al)(Bh+Bl) ~= Ah*Bh + Ah*Bl + Al*Bh
__device__ inline f4v MM3(s8v ah, s8v al, s8v bh, s8v bl, f4v c) {
  c = MM(ah, bh, c);
  c = MM(ah, bl, c);
  c = MM(al, bh, c);
  return c;
}

// ---------------- Kernel 1: per-chunk work + fused per-head scan tail.
__global__ __launch_bounds__(256, 2) void k_chunk(
    const float4* __restrict__ Q4, const float4* __restrict__ K4,
    const float* __restrict__ Kg, const float* __restrict__ Vg,
    const float* __restrict__ gate, const float* __restrict__ eta,
    const float4* __restrict__ W04, const float* __restrict__ gamma,
    const float* __restrict__ beta, const float* __restrict__ W0f,
    float* __restrict__ Ut, float* __restrict__ Pg, float* __restrict__ Gc,
    float* __restrict__ Wpt, int* __restrict__ Cnt, float* __restrict__ Out)
{
  __shared__ __align__(16) short Khi[4096];  // k rows hi (A M2; B M1); after bar2: S hi
  __shared__ __align__(16) short Klo[4096];  // k rows lo;              after bar2: S lo
  __shared__ __align__(16) short KtH[4096];  // k^T [d][j] hi (B M4)
  __shared__ __align__(16) short KtL[4096];  // k^T [d][j] lo
  __shared__ __align__(16) short W0h[4096];  // W0^T [e][d] hi (B M2); after bar2: gt^T hi
  __shared__ __align__(16) short W0l[4096];  // W0^T [e][d] lo;        after bar2: gt^T lo
  __shared__ __align__(16) short GwH[4096];  // (wj*gt)^T [e][j] hi (A M4)
  __shared__ __align__(16) short GwL[4096];  // (wj*gt)^T [e][j] lo
  __shared__ float cl[64];
  __shared__ int lastFlag;

  int tid = threadIdx.x;
  int bid = blockIdx.x;
  int h = bid >> 5;
  int rowb = h * L + (bid & 31) * 64;
  int R = tid >> 6, l = tid & 63, g = l >> 4, c16 = l & 15;
  int arow = 16 * R + c16;
  int kb0 = 16 * g, kb1 = 64 + 16 * g;

  // ---- gate load first (cl scan consumes it soon)
  float gv = gate[rowb + l];

  // ---- staging loads next: first vmcnt waits drain only these
  int g4 = tid & 15;
  float4 kA[2][2], wA[2][2];
  #pragma unroll
  for (int it = 0; it < 2; ++it) {
    int j0 = 2 * ((tid >> 4) + it * 16);
    kA[it][0] = K4[(size_t)(rowb + j0) * 16 + g4];
    kA[it][1] = K4[(size_t)(rowb + j0 + 1) * 16 + g4];
    wA[it][0] = W04[(size_t)h * 1024 + j0 * 16 + g4];
    wA[it][1] = W04[(size_t)h * 1024 + (j0 + 1) * 16 + g4];
  }

  // ---- prefetches (consumed after bar1 / after M2)
  const float4* qp = Q4 + (size_t)(rowb + arow) * 16;
  float4 qA0 = qp[2 * g], qA1 = qp[2 * g + 1], qA2 = qp[8 + 2 * g], qA3 = qp[8 + 2 * g + 1];
  float kk[4][4], vv[4][4], er[4];
  #pragma unroll
  for (int r = 0; r < 4; ++r) {
    int jr = 16 * R + 4 * g + r;
    const float* kp = Kg + (size_t)(rowb + jr) * 64 + c16;
    const float* vp = Vg + (size_t)(rowb + jr) * 64 + c16;
    #pragma unroll
    for (int ct = 0; ct < 4; ++ct) {
      kk[r][ct] = kp[16 * ct];
      vv[r][ct] = vp[16 * ct];
    }
    er[r] = eta[rowb + jr];
  }

  // ---- gate log-cumsum (per wave redundantly; each wave writes all 64 cl)
  float c63v;
  {
    float x = logf(fmaxf(gv, 1e-37f));
    #pragma unroll
    for (int off = 1; off < 64; off <<= 1) {
      float n = __shfl_up(x, off, 64);
      if (l >= off) x += n;
    }
    cl[l] = x;
    c63v = __shfl(x, 63, 64);
    if (R == 0) Pg[rowb + l] = expf(x);
    if (tid == 63) Gc[bid] = expf(x);
  }

  // ---- stage: k rows hi/lo, k^T (same splits reused), W0^T
  #pragma unroll
  for (int it = 0; it < 2; ++it) {
    int j0 = 2 * ((tid >> 4) + it * 16);
    float ke0[4] = {kA[it][0].x, kA[it][0].y, kA[it][0].z, kA[it][0].w};
    float ke1[4] = {kA[it][1].x, kA[it][1].y, kA[it][1].z, kA[it][1].w};
    float we0[4] = {wA[it][0].x, wA[it][0].y, wA[it][0].z, wA[it][0].w};
    float we1[4] = {wA[it][1].x, wA[it][1].y, wA[it][1].z, wA[it][1].w};
    s4v kh0, kl0, kh1, kl1;
    #pragma unroll
    for (int e = 0; e < 4; ++e) {
      unsigned short hb0 = f2bf(ke0[e]);
      unsigned short lb0 = f2bf(ke0[e] - bf2f(hb0));
      unsigned short hb1 = f2bf(ke1[e]);
      unsigned short lb1 = f2bf(ke1[e] - bf2f(hb1));
      kh0[e] = (short)hb0; kl0[e] = (short)lb0;
      kh1[e] = (short)hb1; kl1[e] = (short)lb1;
      int dr = 4 * g4 + e;
      st2(KtH, dr, 2 * j0, (unsigned)hb0 | ((unsigned)hb1 << 16));
      st2(KtL, dr, 2 * j0, (unsigned)lb0 | ((unsigned)lb1 << 16));
      unsigned short wh0 = f2bf(we0[e]), wh1 = f2bf(we1[e]);
      st2(W0h, dr, 2 * j0, (unsigned)wh0 | ((unsigned)wh1 << 16));
      st2(W0l, dr, 2 * j0,
          (unsigned)f2bf(we0[e] - bf2f(wh0)) | ((unsigned)f2bf(we1[e] - bf2f(wh1)) << 16));
    }
    st4(Khi, j0, 8 * g4, kh0); st4(Klo, j0, 8 * g4, kl0);
    st4(Khi, j0 + 1, 8 * g4, kh1); st4(Klo, j0 + 1, 8 * g4, kl1);
  }

  // ---- split q A-fragments in registers
  s8v aQh0, aQl0, aQh1, aQl1;
  {
    float q0[8] = {qA0.x, qA0.y, qA0.z, qA0.w, qA1.x, qA1.y, qA1.z, qA1.w};
    float q1[8] = {qA2.x, qA2.y, qA2.z, qA2.w, qA3.x, qA3.y, qA3.z, qA3.w};
    #pragma unroll
    for (int e = 0; e < 8; ++e) {
      unsigned short hb = f2bf(q0[e]);
      aQh0[e] = (short)hb; aQl0[e] = (short)f2bf(q0[e] - bf2f(hb));
      unsigned short hb1 = f2bf(q1[e]);
      aQh1[e] = (short)hb1; aQl1[e] = (short)f2bf(q1[e] - bf2f(hb1));
    }
  }
  __syncthreads();   // bar1: tiles staged

  // ---- M1: S = QK^T (split x split)
  f4v accS[4];
  #pragma unroll
  for (int ct = 0; ct < 4; ++ct) {
    int br = 16 * ct + c16;
    f4v a = {0.f, 0.f, 0.f, 0.f};
    a = MM3(aQh0, aQl0, ld8(Khi, br, kb0), ld8(Klo, br, kb0), a);
    a = MM3(aQh1, aQl1, ld8(Khi, br, kb1), ld8(Klo, br, kb1), a);
    accS[ct] = a;
  }

  // ---- M2: Z1 = K @ W0 (split x split)
  s8v aKh0 = ld8(Khi, arow, kb0), aKh1 = ld8(Khi, arow, kb1);
  s8v aKl0 = ld8(Klo, arow, kb0), aKl1 = ld8(Klo, arow, kb1);
  f4v accZ[4];
  #pragma unroll
  for (int ct = 0; ct < 4; ++ct) {
    int br = 16 * ct + c16;
    f4v a = {0.f, 0.f, 0.f, 0.f};
    a = MM3(aKh0, aKl0, ld8(W0h, br, kb0), ld8(W0l, br, kb0), a);
    a = MM3(aKh1, aKl1, ld8(W0h, br, kb1), ld8(W0l, br, kb1), a);
    accZ[ct] = a;
  }

  // ---- LN-L2 backward; k,v,eta in regs; wjr from c63v - cli (no wj array)
  float ga[4], be[4];
  #pragma unroll
  for (int ct = 0; ct < 4; ++ct) {
    ga[ct] = gamma[h * 64 + 16 * ct + c16];
    be[ct] = beta[h * 64 + 16 * ct + c16];
  }
  float cli[4], wjr[4];
  #pragma unroll
  for (int r = 0; r < 4; ++r) {
    cli[r] = cl[16 * R + 4 * g + r];
    wjr[r] = expf(c63v - cli[r]);
  }
  float gtreg[4][4];
  #pragma unroll
  for (int r = 0; r < 4; ++r) {
    float s1 = accZ[0][r] + accZ[1][r] + accZ[2][r] + accZ[3][r];
    red16(s1);
    float mu = s1 * (1.f / 64.f);
    float dv[4], s2 = 0.f;
    #pragma unroll
    for (int ct = 0; ct < 4; ++ct) { dv[ct] = accZ[ct][r] - mu; s2 += dv[ct] * dv[ct]; }
    red16(s2);
    float rstd = rsqrtf(s2 * (1.f / 64.f) + 1e-6f);
    float xh[4], gxh[4], t1 = 0.f, t2 = 0.f;
    #pragma unroll
    for (int ct = 0; ct < 4; ++ct) {
      xh[ct] = dv[ct] * rstd;
      float go = 2.f * (fmaf(ga[ct], xh[ct], be[ct]) + kk[r][ct] - vv[r][ct]);
      gxh[ct] = go * ga[ct];
      t1 += gxh[ct];
      t2 += gxh[ct] * xh[ct];
    }
    red16(t1);
    red16(t2);
    float m1 = t1 * (1.f / 64.f), m2 = t2 * (1.f / 64.f);
    #pragma unroll
    for (int ct = 0; ct < 4; ++ct)
      gtreg[r][ct] = -er[r] * (gxh[ct] - m1 - xh[ct] * m2) * rstd;
  }
  __syncthreads();   // bar2: K-row and W0 tiles dead

  // ---- gt^T -> W0 tiles; (wj*gt)^T -> Gw tiles; decayed+masked S -> K tiles
  #pragma unroll
  for (int ct = 0; ct < 4; ++ct) {
    s4v gh, gl, uh, ul;
    #pragma unroll
    for (int r = 0; r < 4; ++r) {
      float gtv = gtreg[r][ct];
      unsigned short hb = f2bf(gtv);
      gh[r] = (short)hb;
      gl[r] = (short)f2bf(gtv - bf2f(hb));
      float gw = gtv * wjr[r];
      unsigned short hb2 = f2bf(gw);
      uh[r] = (short)hb2;
      ul[r] = (short)f2bf(gw - bf2f(hb2));
    }
    int er2 = 16 * ct + c16, cb = 2 * (16 * R + 4 * g);
    st4(W0h, er2, cb, gh); st4(W0l, er2, cb, gl);
    st4(GwH, er2, cb, uh); st4(GwL, er2, cb, ul);
  }
  #pragma unroll
  for (int ct = 0; ct < 4; ++ct) {
    int j = 16 * ct + c16;
    float clj = cl[j];
    #pragma unroll
    for (int r = 0; r < 4; ++r) {
      int i = 16 * R + 4 * g + r;
      float s = (j <= i) ? accS[ct][r] * expf(cli[r] - clj) : 0.f;
      unsigned short hb = f2bf(s);
      st1(Khi, i, 2 * j, hb);
      st1(Klo, i, 2 * j, f2bf(s - bf2f(hb)));
    }
  }
  __syncthreads();   // bar3

  // ---- M3: Intra[i][e] = S·gt -> Out
  s8v aSh0 = ld8(Khi, arow, kb0), aSh1 = ld8(Khi, arow, kb1);
  s8v aSl0 = ld8(Klo, arow, kb0), aSl1 = ld8(Klo, arow, kb1);
  #pragma unroll
  for (int ct = 0; ct < 4; ++ct) {
    int br = 16 * ct + c16;
    f4v a = {0.f, 0.f, 0.f, 0.f};
    a = MM3(aSh0, aSl0, ld8(W0h, br, kb0), ld8(W0l, br, kb0), a);
    a = MM3(aSh1, aSl1, ld8(W0h, br, kb1), ld8(W0l, br, kb1), a);
    #pragma unroll
    for (int r = 0; r < 4; ++r)
      Out[(size_t)(rowb + 16 * R + 4 * g + r) * 64 + 16 * ct + c16] = a[r];
  }

  // ---- M4: U^T[e][d] = (wj*gt)^T · k^T -> Ut
  float* ub = Ut + (size_t)bid * 4096;
  s8v aGh0 = ld8(GwH, arow, kb0), aGh1 = ld8(GwH, arow, kb1);
  s8v aGl0 = ld8(GwL, arow, kb0), aGl1 = ld8(GwL, arow, kb1);
  #pragma unroll
  for (int ct = 0; ct < 4; ++ct) {
    int br = 16 * ct + c16;
    f4v a = {0.f, 0.f, 0.f, 0.f};
    a = MM3(aGh0, aGl0, ld8(KtH, br, kb0), ld8(KtL, br, kb0), a);
    a = MM3(aGh1, aGl1, ld8(KtH, br, kb1), ld8(KtL, br, kb1), a);
    #pragma unroll
    for (int r = 0; r < 4; ++r)
      ub[(16 * R + 4 * g + r) * 64 + 16 * ct + c16] = a[r];
  }

  // ---- fused per-head scan: last block of head h does the 32-step scan.
  // __syncthreads drains each wave's stores to L2; tid0's threadfence makes
  // them device-visible (release); the last arriver acquires and reads Ut.
  __syncthreads();
  if (tid == 0) {
    __threadfence();
    lastFlag = (atomicAdd(&Cnt[h], 1) == NC - 1) ? 1 : 0;
  }
  __syncthreads();
  if (lastFlag) {
    __threadfence();   // acquire: invalidate stale lines
    const float4* ut4 = (const float4*)Ut + (size_t)h * NC * 1024;
    float4* wp4 = (float4*)Wpt + (size_t)h * NC * 1024;
    const float* gcp = Gc + h * NC;
    float4 w[4];
    #pragma unroll
    for (int j = 0; j < 4; ++j) {
      int e4 = tid + j * 256;
      int erow = e4 >> 4, d0 = (e4 & 15) * 4;
      const float* w0p = W0f + (size_t)h * 4096 + erow;
      w[j].x = w0p[(d0 + 0) * 64];
      w[j].y = w0p[(d0 + 1) * 64];
      w[j].z = w0p[(d0 + 2) * 64];
      w[j].w = w0p[(d0 + 3) * 64];
    }
    for (int c2 = 0; c2 < NC; ++c2) {
      float gcv = gcp[c2];
      #pragma unroll
      for (int j = 0; j < 4; ++j) {
        size_t off = (size_t)c2 * 1024 + tid + j * 256;
        wp4[off] = w[j];
        float4 u = ut4[off];
        w[j].x = fmaf(gcv, w[j].x, u.x);
        w[j].y = fmaf(gcv, w[j].y, u.y);
        w[j].z = fmaf(gcv, w[j].z, u.z);
        w[j].w = fmaf(gcv, w[j].w, u.w);
      }
    }
  }
}

// ---------------- Kernel 2: Zq = Pg*(q @ Wprev) + Intra ; LN fwd ; +q
__global__ __launch_bounds__(256, 2) void k_out(
    const float4* __restrict__ Q4, const float* __restrict__ Qg,
    const float4* __restrict__ Wpt4, const float* __restrict__ Pg,
    const float* __restrict__ gamma, const float* __restrict__ beta,
    float* __restrict__ Out)
{
  __shared__ __align__(16) short Whi[4096];
  __shared__ __align__(16) short Wlo[4096];
  int tid = threadIdx.x;
  int h = blockIdx.x >> 5, c = blockIdx.x & 31;
  int rowb = h * L + c * 64;
  int R = tid >> 6, l = tid & 63, g = l >> 4, c16 = l & 15;
  int arow = 16 * R + c16;
  int kb0 = 16 * g, kb1 = 64 + 16 * g;

  const float4* qp = Q4 + (size_t)(rowb + arow) * 16;
  float4 qA0 = qp[2 * g], qA1 = qp[2 * g + 1], qA2 = qp[8 + 2 * g], qA3 = qp[8 + 2 * g + 1];
  float io[4][4], qres[4][4], pr[4];
  #pragma unroll
  for (int r = 0; r < 4; ++r) {
    int row = rowb + 16 * R + 4 * g + r;
    pr[r] = Pg[row];
    #pragma unroll
    for (int ct = 0; ct < 4; ++ct) {
      io[r][ct] = Out[(size_t)row * 64 + 16 * ct + c16];
      qres[r][ct] = Qg[(size_t)row * 64 + 16 * ct + c16];
    }
  }

  for (int idx = tid; idx < 1024; idx += 256) {
    int row = idx >> 4, g4 = idx & 15;
    float4 wv = Wpt4[(size_t)(h * NC + c) * 1024 + idx];
    float we[4] = {wv.x, wv.y, wv.z, wv.w};
    s4v wh, wl;
    #pragma unroll
    for (int e = 0; e < 4; ++e) {
      unsigned short hb = f2bf(we[e]);
      wh[e] = (short)hb;
      wl[e] = (short)f2bf(we[e] - bf2f(hb));
    }
    st4(Whi, row, 8 * g4, wh);
    st4(Wlo, row, 8 * g4, wl);
  }

  s8v ah0, al0, ah1, al1;
  {
    float q0[8] = {qA0.x, qA0.y, qA0.z, qA0.w, qA1.x, qA1.y, qA1.z, qA1.w};
    float q1[8] = {qA2.x, qA2.y, qA2.z, qA2.w, qA3.x, qA3.y, qA3.z, qA3.w};
    #pragma unroll
    for (int e = 0; e < 8; ++e) {
      unsigned short hb = f2bf(q0[e]);
      ah0[e] = (short)hb; al0[e] = (short)f2bf(q0[e] - bf2f(hb));
      unsigned short hb1 = f2bf(q1[e]);
      ah1[e] = (short)hb1; al1[e] = (short)f2bf(q1[e] - bf2f(hb1));
    }
  }
  __syncthreads();

  f4v acc[4];
  #pragma unroll
  for (int ct = 0; ct < 4; ++ct) {
    int br = 16 * ct + c16;
    f4v a = {0.f, 0.f, 0.f, 0.f};
    a = MM3(ah0, al0, ld8(Whi, br, kb0), ld8(Wlo, br, kb0), a);
    a = MM3(ah1, al1, ld8(Whi, br, kb1), ld8(Wlo, br, kb1), a);
    acc[ct] = a;
  }
  float ga[4], be[4];
  #pragma unroll
  for (int ct = 0; ct < 4; ++ct) {
    ga[ct] = gamma[h * 64 + 16 * ct + c16];
    be[ct] = beta[h * 64 + 16 * ct + c16];
  }
  #pragma unroll
  for (int r = 0; r < 4; ++r) {
    int row = rowb + 16 * R + 4 * g + r;
    float zq[4];
    #pragma unroll
    for (int ct = 0; ct < 4; ++ct)
      zq[ct] = fmaf(pr[r], acc[ct][r], io[r][ct]);
    float s1 = zq[0] + zq[1] + zq[2] + zq[3];
    red16(s1);
    float mu = s1 * (1.f / 64.f);
    float dv[4], s2 = 0.f;
    #pragma unroll
    for (int ct = 0; ct < 4; ++ct) { dv[ct] = zq[ct] - mu; s2 += dv[ct] * dv[ct]; }
    red16(s2);
    float rstd = rsqrtf(s2 * (1.f / 64.f) + 1e-6f);
    #pragma unroll
    for (int ct = 0; ct < 4; ++ct) {
      float o = fmaf(ga[ct], dv[ct] * rstd, be[ct]) + qres[r][ct];
      Out[(size_t)row * 64 + 16 * ct + c16] = o;
    }
  }
}

extern "C" void kernel_launch(void* const* d_in, const int* in_sizes, int n_in,
                              void* d_out, int out_size, void* d_ws, size_t ws_size,
                              hipStream_t stream) {
  const float* q     = (const float*)d_in[0];
  const float* k     = (const float*)d_in[1];
  const float* v     = (const float*)d_in[2];
  const float* gate  = (const float*)d_in[3];
  const float* eta   = (const float*)d_in[4];
  const float* W0    = (const float*)d_in[5];
  const float* gamma = (const float*)d_in[6];
  const float* beta  = (const float*)d_in[7];
  float* out = (float*)d_out;
  float* ws  = (float*)d_ws;

  float* Pg  = ws;                         // 32768 floats
  float* Gc  = ws + 32768;                 // 512 floats
  float* Ut  = ws + 33280;                 // 2097152 floats
  float* Wpt = ws + 33280 + 2097152;       // 2097152 floats
  int*   Cnt = (int*)(ws + 33280 + 2 * 2097152);  // 16 ints

  hipMemsetAsync(Cnt, 0, H * sizeof(int), stream);
  k_chunk<<<H * NC, 256, 0, stream>>>(
      (const float4*)q, (const float4*)k, k, v, gate, eta,
      (const float4*)W0, gamma, beta, W0,
      Ut, Pg, Gc, Wpt, Cnt, out);
  k_out<<<H * NC, 256, 0, stream>>>(
      (const float4*)q, q, (const float4*)Wpt, Pg, gamma, beta, out);
}

// Round 11
// 33.279 us; speedup vs baseline: 7.0556x; 2.3497x over previous
//
#include <hip/hip_runtime.h>
#include <hip/hip_bf16.h>
#include <math.h>

// B=1, H=16, L=2048, D=64. Chunked gated recurrence, chunk C=64, NC=32.
// 3 dispatches (R8 structure — fusion via grid-sync (R9) and atomic-tail (R10)
// both measured as large regressions on 8-XCD MI355X).
// NEW: 512-thread blocks (8 waves), one chunk per block -> 16 waves/CU
// (4/SIMD), 2x the occupancy of the 4-wave version. Wave (RG=w>>1, CH=w&1)
// computes 16 rows x 32 cols (2 MFMA tiles) of each matmul. LN row-reductions
// span the two CH-waves: single-pass variance (Sum z, Sum z^2) + moment sums
// exchanged via small LDS buffers (2 extra barriers).
// All 64^3 matmuls: v_mfma_f32_16x16x32_bf16, FULL hi/lo split-bf16 (3-MFMA
// emulation ~2^-17 rel err) on every operand (LN amplifies relative error).
// LDS: 6 bf16 tiles [64][128B] XOR-swizzled (byte ^= (row&7)<<4) + 2KB
// exchange = 51.5KB -> 2 blocks/CU. A row-major [M][K], B transposed [N][K]:
// one ds_read_b128 per fragment. C/D: row=4*(l>>4)+reg, col=l&15 (m89).

#define H 16
#define L 2048
#define D 64
#define NC 32

typedef short s8v __attribute__((ext_vector_type(8)));
typedef short s4v __attribute__((ext_vector_type(4)));
typedef float f4v __attribute__((ext_vector_type(4)));

__device__ inline unsigned short f2bf(float x) {
  unsigned u = __float_as_uint(x);
  return (unsigned short)((u + 0x7fffu + ((u >> 16) & 1u)) >> 16);
}
__device__ inline float bf2f(unsigned short s) { return __uint_as_float(((unsigned)s) << 16); }

__device__ inline int swz(int row, int colByte) { return row * 128 + (colByte ^ ((row & 7) << 4)); }

__device__ inline s8v ld8(const short* base, int row, int colByte) {
  return *(const s8v*)((const char*)base + swz(row, colByte));
}
__device__ inline void st4(short* base, int row, int colByte, s4v v) {
  *(s4v*)((char*)base + swz(row, colByte)) = v;
}
__device__ inline void st2(short* base, int row, int colByte, unsigned v) {
  *(unsigned*)((char*)base + swz(row, colByte)) = v;
}
__device__ inline void st1(short* base, int row, int colByte, unsigned short v) {
  *(short*)((char*)base + swz(row, colByte)) = (short)v;
}

__device__ inline void red16(float& x) {
  x += __shfl_xor(x, 1, 64);
  x += __shfl_xor(x, 2, 64);
  x += __shfl_xor(x, 4, 64);
  x += __shfl_xor(x, 8, 64);
}

__device__ inline f4v MM(s8v a, s8v b, f4v c) {
  return __builtin_amdgcn_mfma_f32_16x16x32_bf16(a, b, c, 0, 0, 0);
}
// 3-MFMA split product: (Ah+Al)(Bh+Bl) ~= Ah*Bh + Ah*Bl + Al*Bh
__device__ inline f4v MM3(s8v ah, s8v al, s8v bh, s8v bl, f4v c) {
  c = MM(ah, bh, c);
  c = MM(ah, bl, c);
  c = MM(al, bh, c);
  return c;
}

// ---------------- Kernel 1: per-chunk gradl + QK^T + decay + Intra + U^T.
__global__ __launch_bounds__(512, 4) void k_chunk(
    const float4* __restrict__ Q4, const float4* __restrict__ K4,
    const float* __restrict__ Kg, const float* __restrict__ Vg,
    const float* __restrict__ gate, const float* __restrict__ eta,
    const float4* __restrict__ W04, const float* __restrict__ gamma,
    const float* __restrict__ beta,
    float* __restrict__ Ut, float* __restrict__ Pg, float* __restrict__ Out)
{
  __shared__ __align__(16) short Khi[4096];  // k rows hi (A M2; B M1); after barX2: S hi
  __shared__ __align__(16) short Klo[4096];  // k rows lo;              after barX2: S lo
  __shared__ __align__(16) short KtH[4096];  // k^T [d][j] hi (B M4)
  __shared__ __align__(16) short KtL[4096];  // k^T [d][j] lo
  __shared__ __align__(16) short W0h[4096];  // W0^T [e][d] hi (B M2); after barX2: gt^T hi
  __shared__ __align__(16) short W0l[4096];  // W0^T [e][d] lo;        after barX2: gt^T lo
  __shared__ __align__(16) short GwH[4096];  // (wj*gt)^T [e][j] hi (A M4)
  __shared__ __align__(16) short GwL[4096];  // (wj*gt)^T [e][j] lo
  __shared__ float cl[64];
  __shared__ float exA[2][64], exB[2][64], exC[2][64], exD[2][64];

  int tid = threadIdx.x;
  int h = blockIdx.x >> 5;
  int rowb = h * L + (blockIdx.x & 31) * 64;
  int w = tid >> 6, l = tid & 63;
  int RG = w >> 1, CH = w & 1;
  int g = l >> 4, c16 = l & 15;
  int arow = 16 * RG + c16;
  int kb0 = 16 * g, kb1 = 64 + 16 * g;

  // ---- gate load first
  float gv = gate[rowb + l];

  // ---- staging loads (first vmcnt waits drain only these)
  int pairI = tid >> 4, g4 = tid & 15;
  int j0 = 2 * pairI, j1 = j0 + 1;
  float4 kA0 = K4[(size_t)(rowb + j0) * 16 + g4];
  float4 kA1 = K4[(size_t)(rowb + j1) * 16 + g4];
  float4 wA0 = W04[(size_t)h * 1024 + j0 * 16 + g4];
  float4 wA1 = W04[(size_t)h * 1024 + j1 * 16 + g4];

  // ---- prefetches (consumed after bar1 / in LN)
  const float4* qp = Q4 + (size_t)(rowb + arow) * 16;
  float4 qA0 = qp[2 * g], qA1 = qp[2 * g + 1], qA2 = qp[8 + 2 * g], qA3 = qp[8 + 2 * g + 1];
  float kk[4][2], vv[4][2], er[4];
  #pragma unroll
  for (int r = 0; r < 4; ++r) {
    int jr = 16 * RG + 4 * g + r;
    const float* kp = Kg + (size_t)(rowb + jr) * 64 + c16;
    const float* vp = Vg + (size_t)(rowb + jr) * 64 + c16;
    #pragma unroll
    for (int j = 0; j < 2; ++j) {
      kk[r][j] = kp[16 * (2 * CH + j)];
      vv[r][j] = vp[16 * (2 * CH + j)];
    }
    er[r] = eta[rowb + jr];
  }

  // ---- gate log-cumsum (redundant per wave)
  float c63v;
  {
    float x = logf(fmaxf(gv, 1e-37f));
    #pragma unroll
    for (int off = 1; off < 64; off <<= 1) {
      float n = __shfl_up(x, off, 64);
      if (l >= off) x += n;
    }
    cl[l] = x;
    c63v = __shfl(x, 63, 64);
    if (w == 0) Pg[rowb + l] = expf(x);
  }

  // ---- stage: k rows hi/lo, k^T, W0^T (b32-packed row pairs; 1 pair/thread)
  {
    float ke0[4] = {kA0.x, kA0.y, kA0.z, kA0.w};
    float ke1[4] = {kA1.x, kA1.y, kA1.z, kA1.w};
    float we0[4] = {wA0.x, wA0.y, wA0.z, wA0.w};
    float we1[4] = {wA1.x, wA1.y, wA1.z, wA1.w};
    s4v kh0, kl0, kh1, kl1;
    #pragma unroll
    for (int e = 0; e < 4; ++e) {
      unsigned short hb0 = f2bf(ke0[e]);
      unsigned short lb0 = f2bf(ke0[e] - bf2f(hb0));
      unsigned short hb1 = f2bf(ke1[e]);
      unsigned short lb1 = f2bf(ke1[e] - bf2f(hb1));
      kh0[e] = (short)hb0; kl0[e] = (short)lb0;
      kh1[e] = (short)hb1; kl1[e] = (short)lb1;
      int dr = 4 * g4 + e;
      st2(KtH, dr, 2 * j0, (unsigned)hb0 | ((unsigned)hb1 << 16));
      st2(KtL, dr, 2 * j0, (unsigned)lb0 | ((unsigned)lb1 << 16));
      unsigned short wh0 = f2bf(we0[e]), wh1 = f2bf(we1[e]);
      st2(W0h, dr, 2 * j0, (unsigned)wh0 | ((unsigned)wh1 << 16));
      st2(W0l, dr, 2 * j0,
          (unsigned)f2bf(we0[e] - bf2f(wh0)) | ((unsigned)f2bf(we1[e] - bf2f(wh1)) << 16));
    }
    st4(Khi, j0, 8 * g4, kh0); st4(Klo, j0, 8 * g4, kl0);
    st4(Khi, j1, 8 * g4, kh1); st4(Klo, j1, 8 * g4, kl1);
  }

  // ---- split q A-fragments in registers
  s8v aQh0, aQl0, aQh1, aQl1;
  {
    float q0[8] = {qA0.x, qA0.y, qA0.z, qA0.w, qA1.x, qA1.y, qA1.z, qA1.w};
    float q1[8] = {qA2.x, qA2.y, qA2.z, qA2.w, qA3.x, qA3.y, qA3.z, qA3.w};
    #pragma unroll
    for (int e = 0; e < 8; ++e) {
      unsigned short hb = f2bf(q0[e]);
      aQh0[e] = (short)hb; aQl0[e] = (short)f2bf(q0[e] - bf2f(hb));
      unsigned short hb1 = f2bf(q1[e]);
      aQh1[e] = (short)hb1; aQl1[e] = (short)f2bf(q1[e] - bf2f(hb1));
    }
  }
  __syncthreads();   // bar1: tiles staged

  // ---- M1: S = QK^T (split x split), 2 ct tiles for this wave's col-half
  f4v accS[2];
  #pragma unroll
  for (int ct2 = 0; ct2 < 2; ++ct2) {
    int br = 16 * (2 * CH + ct2) + c16;
    f4v a = {0.f, 0.f, 0.f, 0.f};
    a = MM3(aQh0, aQl0, ld8(Khi, br, kb0), ld8(Klo, br, kb0), a);
    a = MM3(aQh1, aQl1, ld8(Khi, br, kb1), ld8(Klo, br, kb1), a);
    accS[ct2] = a;
  }

  // ---- M2: Z1 = K @ W0 (split x split), 2 ct tiles
  s8v aKh0 = ld8(Khi, arow, kb0), aKh1 = ld8(Khi, arow, kb1);
  s8v aKl0 = ld8(Klo, arow, kb0), aKl1 = ld8(Klo, arow, kb1);
  f4v accZ[2];
  #pragma unroll
  for (int ct2 = 0; ct2 < 2; ++ct2) {
    int br = 16 * (2 * CH + ct2) + c16;
    f4v a = {0.f, 0.f, 0.f, 0.f};
    a = MM3(aKh0, aKl0, ld8(W0h, br, kb0), ld8(W0l, br, kb0), a);
    a = MM3(aKh1, aKl1, ld8(W0h, br, kb1), ld8(W0l, br, kb1), a);
    accZ[ct2] = a;
  }

  // ---- LN-L2 backward, cross-wave (CH pair) via LDS exchange.
  float ga2[2], be2[2];
  #pragma unroll
  for (int j = 0; j < 2; ++j) {
    ga2[j] = gamma[h * 64 + 16 * (2 * CH + j) + c16];
    be2[j] = beta[h * 64 + 16 * (2 * CH + j) + c16];
  }
  float cli[4], wjr[4];
  #pragma unroll
  for (int r = 0; r < 4; ++r) {
    cli[r] = cl[16 * RG + 4 * g + r];
    wjr[r] = expf(c63v - cli[r]);
  }
  // round 1: Sum z, Sum z^2 over this wave's 32 cols
  #pragma unroll
  for (int r = 0; r < 4; ++r) {
    int jr = 16 * RG + 4 * g + r;
    float z0 = accZ[0][r], z1 = accZ[1][r];
    float p1 = z0 + z1;
    float p2 = z0 * z0 + z1 * z1;
    red16(p1);
    red16(p2);
    if (c16 == 0) { exA[CH][jr] = p1; exB[CH][jr] = p2; }
  }
  __syncthreads();   // barX1 (also: all M1/M2 LDS reads complete)
  float mu[4], rs[4], xh[4][2], gxh[4][2];
  #pragma unroll
  for (int r = 0; r < 4; ++r) {
    int jr = 16 * RG + 4 * g + r;
    float s1 = exA[0][jr] + exA[1][jr];
    float sq = exB[0][jr] + exB[1][jr];
    mu[r] = s1 * (1.f / 64.f);
    float var = sq * (1.f / 64.f) - mu[r] * mu[r];
    rs[r] = rsqrtf(var + 1e-6f);
    float t1 = 0.f, t2 = 0.f;
    #pragma unroll
    for (int j = 0; j < 2; ++j) {
      xh[r][j] = (accZ[j][r] - mu[r]) * rs[r];
      float go = 2.f * (fmaf(ga2[j], xh[r][j], be2[j]) + kk[r][j] - vv[r][j]);
      gxh[r][j] = go * ga2[j];
      t1 += gxh[r][j];
      t2 += gxh[r][j] * xh[r][j];
    }
    red16(t1);
    red16(t2);
    if (c16 == 0) { exC[CH][jr] = t1; exD[CH][jr] = t2; }
  }
  __syncthreads();   // barX2
  float gtreg[4][2];
  #pragma unroll
  for (int r = 0; r < 4; ++r) {
    int jr = 16 * RG + 4 * g + r;
    float m1 = (exC[0][jr] + exC[1][jr]) * (1.f / 64.f);
    float m2 = (exD[0][jr] + exD[1][jr]) * (1.f / 64.f);
    #pragma unroll
    for (int j = 0; j < 2; ++j)
      gtreg[r][j] = -er[r] * (gxh[r][j] - m1 - xh[r][j] * m2) * rs[r];
  }

  // ---- gt^T -> W0 tiles; (wj*gt)^T -> Gw tiles; decayed+masked S -> K tiles
  #pragma unroll
  for (int j = 0; j < 2; ++j) {
    s4v gh, gl, uh, ul;
    #pragma unroll
    for (int r = 0; r < 4; ++r) {
      float gtv = gtreg[r][j];
      unsigned short hb = f2bf(gtv);
      gh[r] = (short)hb;
      gl[r] = (short)f2bf(gtv - bf2f(hb));
      float gw = gtv * wjr[r];
      unsigned short hb2 = f2bf(gw);
      uh[r] = (short)hb2;
      ul[r] = (short)f2bf(gw - bf2f(hb2));
    }
    int er2 = 16 * (2 * CH + j) + c16, cb = 2 * (16 * RG + 4 * g);
    st4(W0h, er2, cb, gh); st4(W0l, er2, cb, gl);
    st4(GwH, er2, cb, uh); st4(GwL, er2, cb, ul);
  }
  #pragma unroll
  for (int j = 0; j < 2; ++j) {
    int jj = 16 * (2 * CH + j) + c16;
    float clj = cl[jj];
    #pragma unroll
    for (int r = 0; r < 4; ++r) {
      int i = 16 * RG + 4 * g + r;
      float s = (jj <= i) ? accS[j][r] * expf(cli[r] - clj) : 0.f;
      unsigned short hb = f2bf(s);
      st1(Khi, i, 2 * jj, hb);
      st1(Klo, i, 2 * jj, f2bf(s - bf2f(hb)));
    }
  }
  __syncthreads();   // bar3: S and gt^T visible

  // ---- M3: Intra[i][e] = S·gt -> Out (2 ct tiles)
  s8v aSh0 = ld8(Khi, arow, kb0), aSh1 = ld8(Khi, arow, kb1);
  s8v aSl0 = ld8(Klo, arow, kb0), aSl1 = ld8(Klo, arow, kb1);
  #pragma unroll
  for (int ct2 = 0; ct2 < 2; ++ct2) {
    int br = 16 * (2 * CH + ct2) + c16;
    f4v a = {0.f, 0.f, 0.f, 0.f};
    a = MM3(aSh0, aSl0, ld8(W0h, br, kb0), ld8(W0l, br, kb0), a);
    a = MM3(aSh1, aSl1, ld8(W0h, br, kb1), ld8(W0l, br, kb1), a);
    #pragma unroll
    for (int r = 0; r < 4; ++r)
      Out[(size_t)(rowb + 16 * RG + 4 * g + r) * 64 + br] = a[r];
  }

  // ---- M4: U^T[e][d] = (wj*gt)^T · k^T -> Ut (2 ct tiles)
  float* ub = Ut + (size_t)blockIdx.x * 4096;
  s8v aGh0 = ld8(GwH, arow, kb0), aGh1 = ld8(GwH, arow, kb1);
  s8v aGl0 = ld8(GwL, arow, kb0), aGl1 = ld8(GwL, arow, kb1);
  #pragma unroll
  for (int ct2 = 0; ct2 < 2; ++ct2) {
    int br = 16 * (2 * CH + ct2) + c16;
    f4v a = {0.f, 0.f, 0.f, 0.f};
    a = MM3(aGh0, aGl0, ld8(KtH, br, kb0), ld8(KtL, br, kb0), a);
    a = MM3(aGh1, aGl1, ld8(KtH, br, kb1), ld8(KtL, br, kb1), a);
    #pragma unroll
    for (int r = 0; r < 4; ++r)
      ub[(16 * RG + 4 * g + r) * 64 + br] = a[r];
  }
}

// ---------------- Kernel 2: chunk-state scan (R8, unchanged).
__global__ __launch_bounds__(256) void k_scan(
    const float* __restrict__ W0, const float* __restrict__ Ut,
    const float* __restrict__ Pg, float* __restrict__ Wpt)
{
  int t = blockIdx.x * 256 + threadIdx.x;
  int h = t >> 12;
  int idx = t & 4095;
  int erow = idx >> 6, d = idx & 63;
  float w = W0[h * 4096 + d * 64 + erow];
  #pragma unroll
  for (int c2 = 0; c2 < NC; ++c2) {
    int off = (h * NC + c2) * 4096 + idx;
    Wpt[off] = w;
    w = fmaf(Pg[h * L + c2 * 64 + 63], w, Ut[off]);
  }
}

// ---------------- Kernel 3: Zq = Pg*(q @ Wprev) + Intra ; LN fwd ; +q (8 waves)
__global__ __launch_bounds__(512, 4) void k_out(
    const float4* __restrict__ Q4, const float* __restrict__ Qg,
    const float4* __restrict__ Wpt4, const float* __restrict__ Pg,
    const float* __restrict__ gamma, const float* __restrict__ beta,
    float* __restrict__ Out)
{
  __shared__ __align__(16) short Whi[4096];
  __shared__ __align__(16) short Wlo[4096];
  __shared__ float exA[2][64], exB[2][64];
  int tid = threadIdx.x;
  int h = blockIdx.x >> 5;
  int rowb = h * L + (blockIdx.x & 31) * 64;
  int w = tid >> 6, l = tid & 63;
  int RG = w >> 1, CH = w & 1;
  int g = l >> 4, c16 = l & 15;
  int arow = 16 * RG + c16;
  int kb0 = 16 * g, kb1 = 64 + 16 * g;

  // ---- staging loads first
  float4 wv0 = Wpt4[(size_t)blockIdx.x * 1024 + tid];
  float4 wv1 = Wpt4[(size_t)blockIdx.x * 1024 + tid + 512];

  // ---- prefetches
  const float4* qp = Q4 + (size_t)(rowb + arow) * 16;
  float4 qA0 = qp[2 * g], qA1 = qp[2 * g + 1], qA2 = qp[8 + 2 * g], qA3 = qp[8 + 2 * g + 1];
  float io[4][2], qres[4][2], pr[4];
  #pragma unroll
  for (int r = 0; r < 4; ++r) {
    int row = rowb + 16 * RG + 4 * g + r;
    pr[r] = Pg[row];
    #pragma unroll
    for (int j = 0; j < 2; ++j) {
      int col = 16 * (2 * CH + j) + c16;
      io[r][j] = Out[(size_t)row * 64 + col];
      qres[r][j] = Qg[(size_t)row * 64 + col];
    }
  }

  // ---- stage Wprev^T split (2 float4 per thread)
  {
    int idx0 = tid, idx1 = tid + 512;
    float we0[4] = {wv0.x, wv0.y, wv0.z, wv0.w};
    float we1[4] = {wv1.x, wv1.y, wv1.z, wv1.w};
    s4v wh0, wl0, wh1, wl1;
    #pragma unroll
    for (int e = 0; e < 4; ++e) {
      unsigned short hb0 = f2bf(we0[e]);
      wh0[e] = (short)hb0; wl0[e] = (short)f2bf(we0[e] - bf2f(hb0));
      unsigned short hb1 = f2bf(we1[e]);
      wh1[e] = (short)hb1; wl1[e] = (short)f2bf(we1[e] - bf2f(hb1));
    }
    st4(Whi, idx0 >> 4, 8 * (idx0 & 15), wh0);
    st4(Wlo, idx0 >> 4, 8 * (idx0 & 15), wl0);
    st4(Whi, idx1 >> 4, 8 * (idx1 & 15), wh1);
    st4(Wlo, idx1 >> 4, 8 * (idx1 & 15), wl1);
  }

  s8v ah0, al0, ah1, al1;
  {
    float q0[8] = {qA0.x, qA0.y, qA0.z, qA0.w, qA1.x, qA1.y, qA1.z, qA1.w};
    float q1[8] = {qA2.x, qA2.y, qA2.z, qA2.w, qA3.x, qA3.y, qA3.z, qA3.w};
    #pragma unroll
    for (int e = 0; e < 8; ++e) {
      unsigned short hb = f2bf(q0[e]);
      ah0[e] = (short)hb; al0[e] = (short)f2bf(q0[e] - bf2f(hb));
      unsigned short hb1 = f2bf(q1[e]);
      ah1[e] = (short)hb1; al1[e] = (short)f2bf(q1[e] - bf2f(hb1));
    }
  }
  __syncthreads();

  f4v acc[2];
  #pragma unroll
  for (int ct2 = 0; ct2 < 2; ++ct2) {
    int br = 16 * (2 * CH + ct2) + c16;
    f4v a = {0.f, 0.f, 0.f, 0.f};
    a = MM3(ah0, al0, ld8(Whi, br, kb0), ld8(Wlo, br, kb0), a);
    a = MM3(ah1, al1, ld8(Whi, br, kb1), ld8(Wlo, br, kb1), a);
    acc[ct2] = a;
  }

  // ---- LN fwd with cross-wave single-pass moments
  float zq[4][2];
  #pragma unroll
  for (int r = 0; r < 4; ++r) {
    int jr = 16 * RG + 4 * g + r;
    float p1 = 0.f, p2 = 0.f;
    #pragma unroll
    for (int j = 0; j < 2; ++j) {
      zq[r][j] = fmaf(pr[r], acc[j][r], io[r][j]);
      p1 += zq[r][j];
      p2 += zq[r][j] * zq[r][j];
    }
    red16(p1);
    red16(p2);
    if (c16 == 0) { exA[CH][jr] = p1; exB[CH][jr] = p2; }
  }
  __syncthreads();
  float ga2[2], be2[2];
  #pragma unroll
  for (int j = 0; j < 2; ++j) {
    ga2[j] = gamma[h * 64 + 16 * (2 * CH + j) + c16];
    be2[j] = beta[h * 64 + 16 * (2 * CH + j) + c16];
  }
  #pragma unroll
  for (int r = 0; r < 4; ++r) {
    int jr = 16 * RG + 4 * g + r;
    int row = rowb + jr;
    float s1 = exA[0][jr] + exA[1][jr];
    float sq = exB[0][jr] + exB[1][jr];
    float mu = s1 * (1.f / 64.f);
    float var = sq * (1.f / 64.f) - mu * mu;
    float rstd = rsqrtf(var + 1e-6f);
    #pragma unroll
    for (int j = 0; j < 2; ++j) {
      int col = 16 * (2 * CH + j) + c16;
      float o = fmaf(ga2[j], (zq[r][j] - mu) * rstd, be2[j]) + qres[r][j];
      Out[(size_t)row * 64 + col] = o;
    }
  }
}

extern "C" void kernel_launch(void* const* d_in, const int* in_sizes, int n_in,
                              void* d_out, int out_size, void* d_ws, size_t ws_size,
                              hipStream_t stream) {
  const float* q     = (const float*)d_in[0];
  const float* k     = (const float*)d_in[1];
  const float* v     = (const float*)d_in[2];
  const float* gate  = (const float*)d_in[3];
  const float* eta   = (const float*)d_in[4];
  const float* W0    = (const float*)d_in[5];
  const float* gamma = (const float*)d_in[6];
  const float* beta  = (const float*)d_in[7];
  float* out = (float*)d_out;
  float* ws  = (float*)d_ws;

  float* Pg  = ws;                         // 32768 floats
  float* Ut  = ws + 32768;                 // 2097152 floats
  float* Wpt = ws + 32768 + 2097152;       // 2097152 floats

  k_chunk<<<H * NC, 512, 0, stream>>>(
      (const float4*)q, (const float4*)k, k, v, gate, eta,
      (const float4*)W0, gamma, beta, Ut, Pg, out);
  k_scan<<<256, 256, 0, stream>>>(W0, Ut, Pg, Wpt);
  k_out<<<H * NC, 512, 0, stream>>>(
      (const float4*)q, q, (const float4*)Wpt, Pg, gamma, beta, out);
}